// Round 7
// baseline (138.241 us; speedup 1.0000x reference)
//
#include <hip/hip_runtime.h>
#include <float.h>
#include <stdint.h>

// Problem constants
#define BATCHES 32
#define P 1024
#define KNN 16
#define C 64
#define H 128
#define N (BATCHES * P)   // 32768
#define SPLITS 8
#define CPS 128           // candidates per split (P / SPLITS)
#define QB 64             // queries per block (= lanes; 1 wave = 1 split)
#define PADH 136          // LDS row pad (272 B stride)

typedef short short8 __attribute__((ext_vector_type(8)));
typedef float floatx4 __attribute__((ext_vector_type(4)));

struct alignas(16) F4 { float x, y, z, w; };

__device__ __forceinline__ unsigned short f2bf(float f) {
    unsigned u = __float_as_uint(f);
    unsigned r = (u + 0x7FFF + ((u >> 16) & 1)) >> 16;   // RNE
    return (unsigned short)r;
}

// ---------------------------------------------------------------------------
// prep: blocks [0,96)    -> WcatT (bf16 [384][64]) + bias_cat (fp32 [384])
//       blocks [96,224)  -> posq[j] = {x,y,z,|p|^2}
//       blocks [224,480) -> V = f2bf(mfma(x, W2)), 128 rows per block.
// V is BIT-IDENTICAL to the original phase-C V path (same f2bf(W_e),
// same f2bf(x) frags, same MFMA, bias 0).
// ---------------------------------------------------------------------------
__global__ __launch_bounds__(256) void prep_kernel(
    const float* __restrict__ W_e, const float* __restrict__ b_e,
    const float* __restrict__ W_sc, const float* __restrict__ b_sc,
    const float* __restrict__ X, const float* __restrict__ pos,
    unsigned short* __restrict__ WT, float* __restrict__ bias,
    F4* __restrict__ posq, unsigned short* __restrict__ V)
{
    __shared__ unsigned short Vs[128][PADH];     // used by V-gemm blocks only
    int b = blockIdx.x;
    int t = threadIdx.x;
    if (b < 96) {
        int i = b * 256 + t;                     // 0 .. 384*64-1
        int col = i >> 6, c = i & 63;
        float w;
        if (col < 128)      w = W_e[c * 128 + col] - W_e[(64 + c) * 128 + col];
        else if (col < 256) w = W_e[(64 + c) * 128 + (col - 128)];
        else                w = W_sc[c * 128 + (col - 256)];
        WT[col * 64 + c] = f2bf(w);
        if (c == 0) {
            bias[col] = (col < 128) ? b_e[col] : (col < 256 ? 0.0f : b_sc[col - 256]);
        }
        return;
    }
    if (b < 224) {
        int j = (b - 96) * 256 + t;              // 0 .. N-1
        float x = pos[j * 3 + 0], y = pos[j * 3 + 1], z = pos[j * 3 + 2];
        float sq = __fadd_rn(__fadd_rn(__fmul_rn(x, x), __fmul_rn(y, y)),
                             __fmul_rn(z, z));
        posq[j] = F4{x, y, z, sq};
        return;
    }

    // ---- V-gemm: rows m0 .. m0+127 ----
    int vb = b - 224;                            // 0..255
    int m0 = vb * 128;
    int w  = t >> 6, ln = t & 63;
    int lm = ln & 15, kg = ln >> 4;

    short8 a0[2], a1[2];
#pragma unroll
    for (int i = 0; i < 2; ++i) {
        int row = m0 + (2 * w + i) * 16 + lm;
        const float4* ar = (const float4*)(X + (size_t)row * 64 + kg * 8);
        float4 f0 = ar[0], f1 = ar[1], f2 = ar[8], f3 = ar[9];
        a0[i][0] = (short)f2bf(f0.x); a0[i][1] = (short)f2bf(f0.y);
        a0[i][2] = (short)f2bf(f0.z); a0[i][3] = (short)f2bf(f0.w);
        a0[i][4] = (short)f2bf(f1.x); a0[i][5] = (short)f2bf(f1.y);
        a0[i][6] = (short)f2bf(f1.z); a0[i][7] = (short)f2bf(f1.w);
        a1[i][0] = (short)f2bf(f2.x); a1[i][1] = (short)f2bf(f2.y);
        a1[i][2] = (short)f2bf(f2.z); a1[i][3] = (short)f2bf(f2.w);
        a1[i][4] = (short)f2bf(f3.x); a1[i][5] = (short)f2bf(f3.y);
        a1[i][6] = (short)f2bf(f3.z); a1[i][7] = (short)f2bf(f3.w);
    }

#pragma unroll 2
    for (int ct = 0; ct < 8; ++ct) {
        int col = ct * 16 + lm;
        short8 b0, b1;
#pragma unroll
        for (int i = 0; i < 8; ++i) {
            b0[i] = (short)f2bf(W_e[(size_t)(64 + kg * 8 + i) * 128 + col]);
            b1[i] = (short)f2bf(W_e[(size_t)(96 + kg * 8 + i) * 128 + col]);
        }
#pragma unroll
        for (int i = 0; i < 2; ++i) {
            floatx4 acc = {0.0f, 0.0f, 0.0f, 0.0f};
            acc = __builtin_amdgcn_mfma_f32_16x16x32_bf16(a0[i], b0, acc, 0, 0, 0);
            acc = __builtin_amdgcn_mfma_f32_16x16x32_bf16(a1[i], b1, acc, 0, 0, 0);
#pragma unroll
            for (int r = 0; r < 4; ++r)
                Vs[(2 * w + i) * 16 + kg * 4 + r][col] = f2bf(acc[r]);
        }
    }
    __syncthreads();

    uint2* Vg = (uint2*)V + (size_t)vb * 4096;   // 128*128*2 B / 8
#pragma unroll
    for (int i = t; i < 4096; i += 256) {
        int row = i >> 5, off = (i & 31) * 4;
        Vg[i] = *(const uint2*)&Vs[row][off];
    }
}

// ---------------------------------------------------------------------------
// knn_gemm_final (fused, scalar-pipe candidates):
//   512 blocks x 512 threads, 64 queries/block (lane = query),
//   8 waves = 8 splits x 128 candidates.
//   phase A/B read candidates via SCALAR loads (wave-uniform addresses
//   pinned with readfirstlane) -> zero LDS/VMEM traffic in the hot loops;
//   dist consumes SGPR operands directly (<=1 SGPR per VALU op).
//   merge = branchless 8-way priority select, full 64 lanes, wave (blk&7).
//   phase C = MFMA gemm U,S -> LDS staging. phase D = V gather + out.
// ---------------------------------------------------------------------------
struct SM {
    union {
        struct {                                 // phase A -> merge -> B
            float lists[SPLITS][16][QB];         // 32768
            unsigned short offs[SPLITS][QB];     // 1024
            unsigned short cnts[SPLITS][QB];     // 1024
            float Tq[QB];                        // 256   => 35072
        };
        struct {                                 // phase C -> D (34816)
            unsigned short Ubuf[QB][PADH];
            unsigned short Sbuf[QB][PADH];
        };
    };
    int nbr[QB][KNN];                            // 4096, phase B -> D
};                                               // 39168 B

__global__ __launch_bounds__(512, 2) void knn_gemm_kernel(
    const F4* __restrict__ posq, const float* __restrict__ X,
    const unsigned short* __restrict__ WT, const float* __restrict__ bias,
    const unsigned short* __restrict__ V,
    float* __restrict__ out)
{
    __shared__ __align__(16) SM A;

    int t = threadIdx.x;
    int q = t & 63;                              // lane = query
    int su = __builtin_amdgcn_readfirstlane(t >> 6);   // wave id = split, SGPR
    int blk = blockIdx.x;
    int batch = blk >> 4;                        // 16 blocks per batch
    int qblk  = blk & 15;
    int iloc  = qblk * QB + q;                   // query local index in batch

    const F4* pq = posq + (size_t)batch * P;     // uniform base (kernel arg)
    F4 me = pq[iloc];                            // per-lane vector load (once)
    const int j0 = su * CPS;                     // uniform

    // ================= phase A: per-split top-16 values =================
    float d[16];
#pragma unroll
    for (int k = 0; k < 16; ++k) d[k] = FLT_MAX;

    auto dist = [&](const F4& c, int j) -> float {
        float dot = __fadd_rn(__fadd_rn(__fmul_rn(me.x, c.x), __fmul_rn(me.y, c.y)),
                              __fmul_rn(me.z, c.z));
        float d2 = __fadd_rn(__fadd_rn(me.w, c.w), __fmul_rn(-2.0f, dot));
        return (j == iloc) ? FLT_MAX : d2;
    };
    auto insert = [&](float d2) {
#pragma unroll
        for (int k = 15; k >= 1; --k)
            d[k] = __builtin_amdgcn_fmed3f(d[k - 1], d2, d[k]);
        d[0] = fminf(d[0], d2);
    };

#pragma unroll 4
    for (int jj = 0; jj < CPS; ++jj) {
        int j = j0 + jj;                         // uniform -> s_load_dwordx4
        F4 c = pq[j];
        insert(dist(c, j));
    }

#pragma unroll
    for (int k = 0; k < 16; ++k) A.lists[su][k][q] = d[k];
    __syncthreads();

    // ---- merge 8 sorted lists -> exact 16th smallest + per-split counts ----
    // Branchless priority select; pops in split order on value ties
    // (== ascending-index tie rule). Wave (blk & 7), all 64 lanes.
    if (su == (blk & 7)) {
        float v[8], wv[8];
        int   n[8];
#pragma unroll
        for (int l = 0; l < 8; ++l) {
            v[l]  = A.lists[l][0][q];
            wv[l] = A.lists[l][1][q];
            n[l]  = 0;
        }
        float T = 0.0f;
#pragma unroll 1
        for (int k = 0; k < 16; ++k) {
            float mn = fminf(fminf(fminf(v[0], v[1]), fminf(v[2], v[3])),
                             fminf(fminf(v[4], v[5]), fminf(v[6], v[7])));
            bool taken = false;
#pragma unroll
            for (int l = 0; l < 8; ++l) {
                bool tk = (!taken) && (v[l] == mn);
                taken = taken || tk;
                int ni = n[l] + (tk ? 1 : 0);
                int ri = ni + 1;
                float rv = A.lists[l][(ri < 16) ? ri : 15][q];  // speculative
                float wnew = (ri < 16) ? rv : FLT_MAX;
                v[l]  = tk ? wv[l] : v[l];
                wv[l] = tk ? wnew  : wv[l];
                n[l]  = ni;
            }
            T = mn;
        }
        A.Tq[q] = T;
        int off = 0;
#pragma unroll
        for (int l = 0; l < 8; ++l) {
            A.offs[l][q] = (unsigned short)off;
            A.cnts[l][q] = (unsigned short)n[l];
            off += n[l];
        }
    }
    __syncthreads();

    // ================= phase B: emit neighbor indices to LDS ================
    {
        float T  = A.Tq[q];
        int   cap = A.cnts[su][q];
        int   ob  = A.offs[su][q];
        int   base = batch * P;
        int   cnt = 0;

#pragma unroll 4
        for (int jj = 0; jj < CPS; ++jj) {
            int j = j0 + jj;                     // uniform -> s_load
            F4 c = pq[j];
            float d2 = dist(c, j);
            if (d2 <= T && cnt < cap) {
                A.nbr[q][ob + cnt] = base + j;   // global row index into V
                cnt++;
            }
        }
    }
    __syncthreads();   // lists/offs/cnts/Tq dead; Ubuf/Sbuf may now alias

    // ================= phase C: gemm for U,S (64 rows) =================
    {
        int w  = t >> 6;                         // wave 0..7
        int ln = t & 63;
        int mt = w & 3, nh = w >> 2;             // m-tile (4), U-vs-S half
        int m0 = blk * QB + mt * 16;
        int lm = ln & 15, kg = ln >> 4;

        const float4* arow = (const float4*)(X + (size_t)(m0 + lm) * 64 + kg * 8);
        float4 f0 = arow[0], f1 = arow[1];       // k = kg*8 .. +8
        float4 f2 = arow[8], f3 = arow[9];       // k = 32+kg*8 .. +8
        short8 a0, a1;
        a0[0] = (short)f2bf(f0.x); a0[1] = (short)f2bf(f0.y);
        a0[2] = (short)f2bf(f0.z); a0[3] = (short)f2bf(f0.w);
        a0[4] = (short)f2bf(f1.x); a0[5] = (short)f2bf(f1.y);
        a0[6] = (short)f2bf(f1.z); a0[7] = (short)f2bf(f1.w);
        a1[0] = (short)f2bf(f2.x); a1[1] = (short)f2bf(f2.y);
        a1[2] = (short)f2bf(f2.z); a1[3] = (short)f2bf(f2.w);
        a1[4] = (short)f2bf(f3.x); a1[5] = (short)f2bf(f3.y);
        a1[6] = (short)f2bf(f3.z); a1[7] = (short)f2bf(f3.w);

        // U tiles: WT cols 0..127 (nt 0..7); S tiles: cols 256..383 (nt 16..23)
        int tbase = (nh == 0) ? 0 : 16;
#pragma unroll 4
        for (int nt = tbase; nt < tbase + 8; ++nt) {
            const short8* brow = (const short8*)(WT + (size_t)(nt * 16 + lm) * 64 + kg * 8);
            short8 b0 = brow[0];
            short8 b1 = brow[4];
            floatx4 acc = {0.0f, 0.0f, 0.0f, 0.0f};
            acc = __builtin_amdgcn_mfma_f32_16x16x32_bf16(a0, b0, acc, 0, 0, 0);
            acc = __builtin_amdgcn_mfma_f32_16x16x32_bf16(a1, b1, acc, 0, 0, 0);

            int col = nt * 16 + lm;
            float bv = bias[col];
#pragma unroll
            for (int r = 0; r < 4; ++r) {
                int row = mt * 16 + kg * 4 + r;
                unsigned short val = f2bf(acc[r] + bv);
                if (col < 128) A.Ubuf[row][col] = val;
                else           A.Sbuf[row][col - 256] = val;
            }
        }
    }
    __syncthreads();

    // ================= phase D: gather V, max-reduce, write out =============
    {
        int pl = t >> 4;                         // 0..31
        int c8 = t & 15;                         // cols 8*c8 .. 8*c8+7
#pragma unroll
        for (int half = 0; half < 2; ++half) {
            int q2 = half * 32 + pl;
            size_t p = (size_t)blk * QB + q2;

            uint4 uu = *(const uint4*)&A.Ubuf[q2][c8 * 8];
            uint4 ss = *(const uint4*)&A.Sbuf[q2][c8 * 8];

            float m0 = -FLT_MAX, m1 = -FLT_MAX, m2 = -FLT_MAX, m3 = -FLT_MAX;
            float m4 = -FLT_MAX, m5 = -FLT_MAX, m6 = -FLT_MAX, m7 = -FLT_MAX;
#pragma unroll
            for (int k = 0; k < KNN; ++k) {
                int row = A.nbr[q2][k];
                uint4 vv = *(const uint4*)(V + (size_t)row * H + c8 * 8);
                m0 = fmaxf(m0, __uint_as_float(vv.x << 16));
                m1 = fmaxf(m1, __uint_as_float(vv.x & 0xFFFF0000u));
                m2 = fmaxf(m2, __uint_as_float(vv.y << 16));
                m3 = fmaxf(m3, __uint_as_float(vv.y & 0xFFFF0000u));
                m4 = fmaxf(m4, __uint_as_float(vv.z << 16));
                m5 = fmaxf(m5, __uint_as_float(vv.z & 0xFFFF0000u));
                m6 = fmaxf(m6, __uint_as_float(vv.w << 16));
                m7 = fmaxf(m7, __uint_as_float(vv.w & 0xFFFF0000u));
            }

            float4 oa, ob;
            oa.x = fmaxf(__uint_as_float(uu.x << 16)         + m0, 0.0f) + __uint_as_float(ss.x << 16);
            oa.y = fmaxf(__uint_as_float(uu.x & 0xFFFF0000u) + m1, 0.0f) + __uint_as_float(ss.x & 0xFFFF0000u);
            oa.z = fmaxf(__uint_as_float(uu.y << 16)         + m2, 0.0f) + __uint_as_float(ss.y << 16);
            oa.w = fmaxf(__uint_as_float(uu.y & 0xFFFF0000u) + m3, 0.0f) + __uint_as_float(ss.y & 0xFFFF0000u);
            ob.x = fmaxf(__uint_as_float(uu.z << 16)         + m4, 0.0f) + __uint_as_float(ss.z << 16);
            ob.y = fmaxf(__uint_as_float(uu.z & 0xFFFF0000u) + m5, 0.0f) + __uint_as_float(ss.z & 0xFFFF0000u);
            ob.z = fmaxf(__uint_as_float(uu.w << 16)         + m6, 0.0f) + __uint_as_float(ss.w << 16);
            ob.w = fmaxf(__uint_as_float(uu.w & 0xFFFF0000u) + m7, 0.0f) + __uint_as_float(ss.w & 0xFFFF0000u);
            ((float4*)(out + p * H))[c8 * 2]     = oa;
            ((float4*)(out + p * H))[c8 * 2 + 1] = ob;
        }
    }
}

// ---------------------------------------------------------------------------
extern "C" void kernel_launch(void* const* d_in, const int* in_sizes, int n_in,
                              void* d_out, int out_size, void* d_ws, size_t ws_size,
                              hipStream_t stream)
{
    const float* x    = (const float*)d_in[0];
    const float* pos  = (const float*)d_in[1];
    // d_in[2] = batch indices (implicit: i / P) -- unused
    const float* W_e  = (const float*)d_in[3];
    const float* b_e  = (const float*)d_in[4];
    const float* W_sc = (const float*)d_in[5];
    const float* b_sc = (const float*)d_in[6];
    float* out = (float*)d_out;

    char* ws = (char*)d_ws;
    // workspace layout (bytes)
    const size_t OFF_V    = 0;                          // N*H*2 = 8 MB
    const size_t OFF_WT   = 8ull << 20;                 // 384*64*2 = 48 KB
    const size_t OFF_BIAS = OFF_WT + 49152;             // 384*4 -> pad 2 KB
    const size_t OFF_POSQ = OFF_BIAS + 2048;            // N*16 = 512 KB

    unsigned short* V    = (unsigned short*)(ws + OFF_V);
    unsigned short* WT   = (unsigned short*)(ws + OFF_WT);
    float*          bias = (float*)(ws + OFF_BIAS);
    F4*             posq = (F4*)(ws + OFF_POSQ);

    prep_kernel<<<224 + N / 128, 256, 0, stream>>>(W_e, b_e, W_sc, b_sc, x, pos,
                                                   WT, bias, posq, V);
    knn_gemm_kernel<<<N / QB, 512, 0, stream>>>(posq, x, WT, bias, V, out);
}

// Round 8
// 130.497 us; speedup vs baseline: 1.0593x; 1.0593x over previous
//
#include <hip/hip_runtime.h>
#include <float.h>
#include <stdint.h>

// Problem constants
#define BATCHES 32
#define P 1024
#define KNN 16
#define C 64
#define H 128
#define N (BATCHES * P)   // 32768
#define SPLITS 8
#define CPS 128           // candidates per split (P / SPLITS)
#define QB 32             // queries per block
#define PADH 136          // LDS row pad (272 B stride)

typedef short short8 __attribute__((ext_vector_type(8)));
typedef float floatx4 __attribute__((ext_vector_type(4)));

struct alignas(16) F4 { float x, y, z, w; };

__device__ __forceinline__ unsigned short f2bf(float f) {
    unsigned u = __float_as_uint(f);
    unsigned r = (u + 0x7FFF + ((u >> 16) & 1)) >> 16;   // RNE
    return (unsigned short)r;
}

// ---------------------------------------------------------------------------
// prep: blocks [0,96)   -> WcatT (bf16 [384][64]) + bias_cat (fp32 [384])
//       blocks [96,352) -> V = f2bf(mfma(x, W2)), 128 rows per block.
// V is BIT-IDENTICAL to the original phase-C V path (same f2bf(W_e) values,
// same f2bf(x) frags, same MFMA, bias 0). W2 is staged through LDS with
// coalesced fp32 reads (the old path did 128 stride-512B scalar loads per
// thread); k-swizzle (k+8h)&63 keeps ds_read_b128 aligned and spreads banks.
// ---------------------------------------------------------------------------
__global__ __launch_bounds__(256) void prep_kernel(
    const float* __restrict__ W_e, const float* __restrict__ b_e,
    const float* __restrict__ W_sc, const float* __restrict__ b_sc,
    const float* __restrict__ X,
    unsigned short* __restrict__ WT, float* __restrict__ bias,
    unsigned short* __restrict__ V)
{
    __shared__ unsigned short Vs[128][PADH];     // V-gemm staging
    __shared__ unsigned short Wb[128 * 64];      // W2 bf16, [h][k swizzled]
    int b = blockIdx.x;
    int t = threadIdx.x;
    if (b < 96) {
        int i = b * 256 + t;                     // 0 .. 384*64-1
        int col = i >> 6, c = i & 63;
        float w;
        if (col < 128)      w = W_e[c * 128 + col] - W_e[(64 + c) * 128 + col];
        else if (col < 256) w = W_e[(64 + c) * 128 + (col - 128)];
        else                w = W_sc[c * 128 + (col - 256)];
        WT[col * 64 + c] = f2bf(w);
        if (c == 0) {
            bias[col] = (col < 128) ? b_e[col] : (col < 256 ? 0.0f : b_sc[col - 256]);
        }
        return;
    }

    // ---- V-gemm: rows m0 .. m0+127 ----
    int vb = b - 96;                             // 0..255
    int m0 = vb * 128;
    int w  = t >> 6, ln = t & 63;
    int lm = ln & 15, kg = ln >> 4;

    // stage W2 (rows 64..127 of W_e) as bf16 [h][k'], coalesced over h
#pragma unroll 8
    for (int i = 0; i < 32; ++i) {
        int m = i * 256 + t;                     // 0..8191
        int k = m >> 7, h = m & 127;
        Wb[h * 64 + ((k + 8 * h) & 63)] = f2bf(W_e[(size_t)(64 + k) * 128 + h]);
    }

    short8 a0[2], a1[2];
#pragma unroll
    for (int i = 0; i < 2; ++i) {
        int row = m0 + (2 * w + i) * 16 + lm;
        const float4* ar = (const float4*)(X + (size_t)row * 64 + kg * 8);
        float4 f0 = ar[0], f1 = ar[1], f2 = ar[8], f3 = ar[9];
        a0[i][0] = (short)f2bf(f0.x); a0[i][1] = (short)f2bf(f0.y);
        a0[i][2] = (short)f2bf(f0.z); a0[i][3] = (short)f2bf(f0.w);
        a0[i][4] = (short)f2bf(f1.x); a0[i][5] = (short)f2bf(f1.y);
        a0[i][6] = (short)f2bf(f1.z); a0[i][7] = (short)f2bf(f1.w);
        a1[i][0] = (short)f2bf(f2.x); a1[i][1] = (short)f2bf(f2.y);
        a1[i][2] = (short)f2bf(f2.z); a1[i][3] = (short)f2bf(f2.w);
        a1[i][4] = (short)f2bf(f3.x); a1[i][5] = (short)f2bf(f3.y);
        a1[i][6] = (short)f2bf(f3.z); a1[i][7] = (short)f2bf(f3.w);
    }
    __syncthreads();

#pragma unroll 2
    for (int ct = 0; ct < 8; ++ct) {
        int col = ct * 16 + lm;
        int sbase = col * 64;
        short8 b0 = *(const short8*)&Wb[sbase + ((8 * (kg + col)) & 63)];
        short8 b1 = *(const short8*)&Wb[sbase + ((8 * (kg + col) + 32) & 63)];
#pragma unroll
        for (int i = 0; i < 2; ++i) {
            floatx4 acc = {0.0f, 0.0f, 0.0f, 0.0f};
            acc = __builtin_amdgcn_mfma_f32_16x16x32_bf16(a0[i], b0, acc, 0, 0, 0);
            acc = __builtin_amdgcn_mfma_f32_16x16x32_bf16(a1[i], b1, acc, 0, 0, 0);
#pragma unroll
            for (int r = 0; r < 4; ++r)
                Vs[(2 * w + i) * 16 + kg * 4 + r][col] = f2bf(acc[r]);
        }
    }
    __syncthreads();

    uint2* Vg = (uint2*)V + (size_t)vb * 4096;   // 128*128*2 B / 8
#pragma unroll
    for (int i = t; i < 4096; i += 256) {
        int row = i >> 5, off = (i & 31) * 4;
        Vg[i] = *(const uint2*)&Vs[row][off];
    }
}

// ---------------------------------------------------------------------------
// knn_gemm_final (fused, R6 structure): 1024 blocks x 256 threads,
// 32 queries/block, 8 splits x 128 candidates.
//   phase A = per-split top-16 (LDS spos); iloc check hoisted: all 32
//             queries live in split (qblk>>2), so only wave (so>>1) runs
//             the checked dist -- 3/4 of waves save 2 VALU/candidate.
//   merge   = branchless 8-way priority select on wave (blk & 3)
//   phase B = recompute dist (same hoist), emit neighbor indices to LDS
//   phase C = MFMA gemm for U,S -> LDS staging
//   phase D = gather V (L2-resident), max-reduce, write out direct.
// ---------------------------------------------------------------------------
struct SM {
    F4 spos[P + 8];                              // 16512 B, dead after phase B
    union {
        struct {                                 // phase A -> merge -> B
            float lists[SPLITS][16][QB];         // 16384
            unsigned short offs[SPLITS][QB];     // 512
            unsigned short cnts[SPLITS][QB];     // 512
            float Tq[QB];                        // 128   => 17536
        };
        struct {                                 // phase C -> D (17408)
            unsigned short Ubuf[QB][PADH];
            unsigned short Sbuf[QB][PADH];
        };
    };
    int nbr[QB][KNN];                            // 2048, phase B -> D
};                                               // total 36096 B -> 4 blk/CU

__global__ __launch_bounds__(256, 4) void knn_gemm_kernel(
    const float* __restrict__ pos, const float* __restrict__ X,
    const unsigned short* __restrict__ WT, const float* __restrict__ bias,
    const unsigned short* __restrict__ V,
    float* __restrict__ out)
{
    __shared__ __align__(16) SM A;

    int t = threadIdx.x;
    int q = t & 31, s = t >> 5;                  // s = split 0..7 (2 per wave)
    int blk = blockIdx.x;
    int batch = blk >> 5;                        // 32 blocks per batch
    int qblk  = blk & 31;
    int iloc  = qblk * QB + q;                   // query local index in batch
    int so    = qblk >> 2;                       // split containing all ilocs
    bool wave_owns = ((t >> 6) == (so >> 1));    // wave covers splits {2w,2w+1}

    // ---- stage spos ----
    const float* pb = pos + (size_t)batch * P * 3;
    for (int j = t; j < P; j += 256) {
        float x = pb[j * 3 + 0], y = pb[j * 3 + 1], z = pb[j * 3 + 2];
        float sq = __fadd_rn(__fadd_rn(__fmul_rn(x, x), __fmul_rn(y, y)),
                             __fmul_rn(z, z));
        A.spos[j] = F4{x, y, z, sq};
    }
    __syncthreads();

    F4 me = A.spos[iloc];
    const int j0 = s * CPS;

    // ================= phase A: per-split top-16 values =================
    float d[16];
#pragma unroll
    for (int k = 0; k < 16; ++k) d[k] = FLT_MAX;

    auto dist_nc = [&](const F4& c) -> float {   // no iloc check
        float dot = __fadd_rn(__fadd_rn(__fmul_rn(me.x, c.x), __fmul_rn(me.y, c.y)),
                              __fmul_rn(me.z, c.z));
        return __fadd_rn(__fadd_rn(me.w, c.w), __fmul_rn(-2.0f, dot));
    };
    auto dist = [&](const F4& c, int j) -> float {
        float d2 = dist_nc(c);
        return (j == iloc) ? FLT_MAX : d2;
    };
    auto insert = [&](float d2) {
#pragma unroll
        for (int k = 15; k >= 1; --k)
            d[k] = __builtin_amdgcn_fmed3f(d[k - 1], d2, d[k]);
        d[0] = fminf(d[0], d2);
    };

    if (wave_owns) {
#pragma unroll 8
        for (int jj = 0; jj < CPS; ++jj) {
            int j = j0 + jj;
            F4 c = A.spos[j];
            insert(dist(c, j));
        }
    } else {
#pragma unroll 8
        for (int jj = 0; jj < CPS; ++jj) {
            F4 c = A.spos[j0 + jj];
            insert(dist_nc(c));
        }
    }

#pragma unroll
    for (int k = 0; k < 16; ++k) A.lists[s][k][q] = d[k];
    __syncthreads();

    // ---- merge 8 sorted lists -> exact 16th smallest + per-split counts ----
    // Branchless priority select; pops in split order on value ties
    // (== ascending-index tie rule). Wave (blk & 3) so concurrent blocks'
    // merges land on different SIMDs.
    if ((t >> 6) == (blk & 3) && (t & 63) < QB) {
        int qm = t & 63;
        float v[8], wv[8];
        int   n[8];
#pragma unroll
        for (int l = 0; l < 8; ++l) {
            v[l]  = A.lists[l][0][qm];
            wv[l] = A.lists[l][1][qm];
            n[l]  = 0;
        }
        float T = 0.0f;
#pragma unroll 1
        for (int k = 0; k < 16; ++k) {
            float mn = fminf(fminf(fminf(v[0], v[1]), fminf(v[2], v[3])),
                             fminf(fminf(v[4], v[5]), fminf(v[6], v[7])));
            bool taken = false;
#pragma unroll
            for (int l = 0; l < 8; ++l) {
                bool tk = (!taken) && (v[l] == mn);
                taken = taken || tk;
                int ni = n[l] + (tk ? 1 : 0);
                int ri = ni + 1;
                float rv = A.lists[l][(ri < 16) ? ri : 15][qm];  // speculative
                float wnew = (ri < 16) ? rv : FLT_MAX;
                v[l]  = tk ? wv[l] : v[l];
                wv[l] = tk ? wnew  : wv[l];
                n[l]  = ni;
            }
            T = mn;
        }
        A.Tq[qm] = T;
        int off = 0;
#pragma unroll
        for (int l = 0; l < 8; ++l) {
            A.offs[l][qm] = (unsigned short)off;
            A.cnts[l][qm] = (unsigned short)n[l];
            off += n[l];
        }
    }
    __syncthreads();

    // ================= phase B: emit neighbor indices to LDS ================
    {
        float T  = A.Tq[q];
        int   cap = A.cnts[s][q];
        int   ob  = A.offs[s][q];
        int   base = batch * P;
        int   cnt = 0;

        if (wave_owns) {
#pragma unroll 4
            for (int jj = 0; jj < CPS; ++jj) {
                int j = j0 + jj;
                F4 c = A.spos[j];
                float d2 = dist(c, j);
                if (d2 <= T && cnt < cap) {
                    A.nbr[q][ob + cnt] = base + j;
                    cnt++;
                }
            }
        } else {
#pragma unroll 4
            for (int jj = 0; jj < CPS; ++jj) {
                int j = j0 + jj;
                F4 c = A.spos[j];
                float d2 = dist_nc(c);
                if (d2 <= T && cnt < cap) {
                    A.nbr[q][ob + cnt] = base + j;
                    cnt++;
                }
            }
        }
    }
    __syncthreads();   // lists/offs/cnts/Tq dead; Ubuf/Sbuf may now alias

    // ================= phase C: gemm for U,S only =================
    {
        int w  = t >> 6;                         // wave 0..3
        int ln = t & 63;
        int mt = w & 1, nh = w >> 1;             // m-tile (2), U-vs-S half
        int m0 = blk * QB + mt * 16;
        int lm = ln & 15, kg = ln >> 4;

        const float4* arow = (const float4*)(X + (size_t)(m0 + lm) * 64 + kg * 8);
        float4 f0 = arow[0], f1 = arow[1];       // k = kg*8 .. +8
        float4 f2 = arow[8], f3 = arow[9];       // k = 32+kg*8 .. +8
        short8 a0, a1;
        a0[0] = (short)f2bf(f0.x); a0[1] = (short)f2bf(f0.y);
        a0[2] = (short)f2bf(f0.z); a0[3] = (short)f2bf(f0.w);
        a0[4] = (short)f2bf(f1.x); a0[5] = (short)f2bf(f1.y);
        a0[6] = (short)f2bf(f1.z); a0[7] = (short)f2bf(f1.w);
        a1[0] = (short)f2bf(f2.x); a1[1] = (short)f2bf(f2.y);
        a1[2] = (short)f2bf(f2.z); a1[3] = (short)f2bf(f2.w);
        a1[4] = (short)f2bf(f3.x); a1[5] = (short)f2bf(f3.y);
        a1[6] = (short)f2bf(f3.z); a1[7] = (short)f2bf(f3.w);

        // U tiles: WT cols 0..127 (nt 0..7); S tiles: cols 256..383 (nt 16..23)
        int tbase = (nh == 0) ? 0 : 16;
#pragma unroll 4
        for (int nt = tbase; nt < tbase + 8; ++nt) {
            const short8* brow = (const short8*)(WT + (size_t)(nt * 16 + lm) * 64 + kg * 8);
            short8 b0 = brow[0];
            short8 b1 = brow[4];
            floatx4 acc = {0.0f, 0.0f, 0.0f, 0.0f};
            acc = __builtin_amdgcn_mfma_f32_16x16x32_bf16(a0, b0, acc, 0, 0, 0);
            acc = __builtin_amdgcn_mfma_f32_16x16x32_bf16(a1, b1, acc, 0, 0, 0);

            int col = nt * 16 + lm;
            float bv = bias[col];
#pragma unroll
            for (int r = 0; r < 4; ++r) {
                int row = mt * 16 + kg * 4 + r;
                unsigned short val = f2bf(acc[r] + bv);
                if (col < 128) A.Ubuf[row][col] = val;
                else           A.Sbuf[row][col - 256] = val;
            }
        }
    }
    __syncthreads();

    // ================= phase D: gather V, max-reduce, write out =============
    {
        int pl = t >> 4;                         // 0..15
        int c8 = t & 15;                         // cols 8*c8 .. 8*c8+7
#pragma unroll
        for (int half = 0; half < 2; ++half) {
            int q2 = half * 16 + pl;
            size_t p = (size_t)blk * QB + q2;

            uint4 uu = *(const uint4*)&A.Ubuf[q2][c8 * 8];
            uint4 ss = *(const uint4*)&A.Sbuf[q2][c8 * 8];

            float m0 = -FLT_MAX, m1 = -FLT_MAX, m2 = -FLT_MAX, m3 = -FLT_MAX;
            float m4 = -FLT_MAX, m5 = -FLT_MAX, m6 = -FLT_MAX, m7 = -FLT_MAX;
#pragma unroll
            for (int k = 0; k < KNN; ++k) {
                int row = A.nbr[q2][k];
                uint4 vv = *(const uint4*)(V + (size_t)row * H + c8 * 8);
                m0 = fmaxf(m0, __uint_as_float(vv.x << 16));
                m1 = fmaxf(m1, __uint_as_float(vv.x & 0xFFFF0000u));
                m2 = fmaxf(m2, __uint_as_float(vv.y << 16));
                m3 = fmaxf(m3, __uint_as_float(vv.y & 0xFFFF0000u));
                m4 = fmaxf(m4, __uint_as_float(vv.z << 16));
                m5 = fmaxf(m5, __uint_as_float(vv.z & 0xFFFF0000u));
                m6 = fmaxf(m6, __uint_as_float(vv.w << 16));
                m7 = fmaxf(m7, __uint_as_float(vv.w & 0xFFFF0000u));
            }

            float4 oa, ob;
            oa.x = fmaxf(__uint_as_float(uu.x << 16)         + m0, 0.0f) + __uint_as_float(ss.x << 16);
            oa.y = fmaxf(__uint_as_float(uu.x & 0xFFFF0000u) + m1, 0.0f) + __uint_as_float(ss.x & 0xFFFF0000u);
            oa.z = fmaxf(__uint_as_float(uu.y << 16)         + m2, 0.0f) + __uint_as_float(ss.y << 16);
            oa.w = fmaxf(__uint_as_float(uu.y & 0xFFFF0000u) + m3, 0.0f) + __uint_as_float(ss.y & 0xFFFF0000u);
            ob.x = fmaxf(__uint_as_float(uu.z << 16)         + m4, 0.0f) + __uint_as_float(ss.z << 16);
            ob.y = fmaxf(__uint_as_float(uu.z & 0xFFFF0000u) + m5, 0.0f) + __uint_as_float(ss.z & 0xFFFF0000u);
            ob.z = fmaxf(__uint_as_float(uu.w << 16)         + m6, 0.0f) + __uint_as_float(ss.w << 16);
            ob.w = fmaxf(__uint_as_float(uu.w & 0xFFFF0000u) + m7, 0.0f) + __uint_as_float(ss.w & 0xFFFF0000u);
            ((float4*)(out + p * H))[c8 * 2]     = oa;
            ((float4*)(out + p * H))[c8 * 2 + 1] = ob;
        }
    }
}

// ---------------------------------------------------------------------------
extern "C" void kernel_launch(void* const* d_in, const int* in_sizes, int n_in,
                              void* d_out, int out_size, void* d_ws, size_t ws_size,
                              hipStream_t stream)
{
    const float* x    = (const float*)d_in[0];
    const float* pos  = (const float*)d_in[1];
    // d_in[2] = batch indices (implicit: i / P) -- unused
    const float* W_e  = (const float*)d_in[3];
    const float* b_e  = (const float*)d_in[4];
    const float* W_sc = (const float*)d_in[5];
    const float* b_sc = (const float*)d_in[6];
    float* out = (float*)d_out;

    char* ws = (char*)d_ws;
    // workspace layout (bytes)
    const size_t OFF_V    = 0;                          // N*H*2 = 8 MB
    const size_t OFF_WT   = 8ull << 20;                 // 384*64*2 = 48 KB
    const size_t OFF_BIAS = OFF_WT + 49152;             // 384*4

    unsigned short* V    = (unsigned short*)(ws + OFF_V);
    unsigned short* WT   = (unsigned short*)(ws + OFF_WT);
    float*          bias = (float*)(ws + OFF_BIAS);

    prep_kernel<<<96 + N / 128, 256, 0, stream>>>(W_e, b_e, W_sc, b_sc, x,
                                                  WT, bias, V);
    knn_gemm_kernel<<<N / QB, 256, 0, stream>>>(pos, x, WT, bias, V, out);
}